// Round 2
// baseline (2021.611 us; speedup 1.0000x reference)
//
#include <hip/hip_runtime.h>
#include <math.h>

#define NN 100000
#define NE 1600000
#define NF 128
#define NOUT 3
#define NEGS 0.02f
#define GEPS 1e-5f

// ---------------- CSR build ----------------
__global__ void k_hist(const int* __restrict__ dst, int* __restrict__ counts) {
    int i = blockIdx.x * blockDim.x + threadIdx.x;
    if (i < NE) atomicAdd(&counts[dst[i]], 1);
}

__global__ void k_scan1(const int* __restrict__ counts, int* __restrict__ bsums) {
    __shared__ int s[256];
    int i = blockIdx.x * 256 + threadIdx.x;
    s[threadIdx.x] = (i < NN) ? counts[i] : 0;
    __syncthreads();
    for (int off = 128; off > 0; off >>= 1) {
        if (threadIdx.x < off) s[threadIdx.x] += s[threadIdx.x + off];
        __syncthreads();
    }
    if (threadIdx.x == 0) bsums[blockIdx.x] = s[0];
}

// one block of 512 threads scans NB (<512) block sums (exclusive)
__global__ void k_scan2(int* __restrict__ bsums, int nb) {
    __shared__ int s[512];
    int t = threadIdx.x;
    int v = (t < nb) ? bsums[t] : 0;
    s[t] = v;
    __syncthreads();
    for (int off = 1; off < 512; off <<= 1) {
        int u = (t >= off) ? s[t - off] : 0;
        __syncthreads();
        s[t] += u;
        __syncthreads();
    }
    if (t < nb) bsums[t] = s[t] - v;   // exclusive
}

__global__ void k_scan3(const int* __restrict__ counts, const int* __restrict__ bsums,
                        int* __restrict__ offsets, int* __restrict__ cursor) {
    __shared__ int s[256];
    int i = blockIdx.x * 256 + threadIdx.x;
    int v = (i < NN) ? counts[i] : 0;
    s[threadIdx.x] = v;
    __syncthreads();
    for (int off = 1; off < 256; off <<= 1) {
        int u = (threadIdx.x >= off) ? s[threadIdx.x - off] : 0;
        __syncthreads();
        s[threadIdx.x] += u;
        __syncthreads();
    }
    int excl = s[threadIdx.x] - v + bsums[blockIdx.x];
    if (i < NN) { offsets[i] = excl; cursor[i] = excl; }
    else if (i == NN) { offsets[i] = excl; }
}

__global__ void k_scatter(const int* __restrict__ src, const int* __restrict__ dst,
                          int* __restrict__ cursor, int* __restrict__ csr) {
    int i = blockIdx.x * blockDim.x + threadIdx.x;
    if (i < NE) {
        int d = dst[i];
        int p = atomicAdd(&cursor[d], 1);
        csr[p] = src[i];
    }
}

// ---------------- max aggregation (CSR) ----------------
__global__ __launch_bounds__(256) void k_aggmax(const float* __restrict__ h,
                                                const int* __restrict__ offsets,
                                                const int* __restrict__ csr,
                                                float* __restrict__ m) {
    int node = blockIdx.x * 2 + (threadIdx.x >> 7);
    int f = threadIdx.x & 127;
    if (node >= NN) return;
    int beg = offsets[node], end = offsets[node + 1];
    float acc = -INFINITY;
    int e = beg;
    for (; e + 4 <= end; e += 4) {
        int s0 = csr[e], s1 = csr[e + 1], s2 = csr[e + 2], s3 = csr[e + 3];
        float v0 = h[s0 * NF + f], v1 = h[s1 * NF + f];
        float v2 = h[s2 * NF + f], v3 = h[s3 * NF + f];
        acc = fmaxf(acc, fmaxf(fmaxf(v0, v1), fmaxf(v2, v3)));
    }
    for (; e < end; ++e) acc = fmaxf(acc, h[csr[e] * NF + f]);
    m[node * NF + f] = (beg == end) ? 0.0f : acc;
}

// ---------------- fused GEMM: Z = m@Wl.T + h@Wr.T + b, plus per-feature stats ----------------
#define KC 32
__global__ __launch_bounds__(256) void k_gemm(const float* __restrict__ Am,
                                              const float* __restrict__ Ah,
                                              const float* __restrict__ Wl,
                                              const float* __restrict__ Wr,
                                              const float* __restrict__ bias,
                                              float* __restrict__ Z,
                                              float* __restrict__ stats) {
    __shared__ __align__(16) float As[KC][68];
    __shared__ __align__(16) float Bs[KC][132];
    int n0 = blockIdx.x * 64;
    int tid = threadIdx.x;
    int ng = tid & 15;   // node group: nodes ng*4 .. ng*4+3
    int og = tid >> 4;   // out group: outs og*8 .. og*8+7

    float acc[4][8];
#pragma unroll
    for (int a = 0; a < 4; a++)
#pragma unroll
        for (int b = 0; b < 8; b++) acc[a][b] = 0.f;

    int ln = tid >> 3;  // 0..31
    int lj = tid & 7;   // float4 slot in 32-wide K chunk

    for (int kc = 0; kc < 8; ++kc) {
        const float* A = (kc < 4) ? Am : Ah;
        const float* W = (kc < 4) ? Wl : Wr;
        int k0 = (kc & 3) * KC;
        // A chunk -> transposed As[k][node]
#pragma unroll
        for (int p = 0; p < 2; p++) {
            int n = n0 + p * 32 + ln;
            int nc = (n < NN) ? n : (NN - 1);
            float4 v = *(const float4*)&A[nc * NF + k0 + lj * 4];
            As[lj * 4 + 0][p * 32 + ln] = v.x;
            As[lj * 4 + 1][p * 32 + ln] = v.y;
            As[lj * 4 + 2][p * 32 + ln] = v.z;
            As[lj * 4 + 3][p * 32 + ln] = v.w;
        }
        // W chunk -> Bs[k][o]
#pragma unroll
        for (int q = 0; q < 4; q++) {
            int o = q * 32 + ln;
            float4 w = *(const float4*)&W[o * NF + k0 + lj * 4];
            Bs[lj * 4 + 0][o] = w.x;
            Bs[lj * 4 + 1][o] = w.y;
            Bs[lj * 4 + 2][o] = w.z;
            Bs[lj * 4 + 3][o] = w.w;
        }
        __syncthreads();
#pragma unroll
        for (int k = 0; k < KC; k++) {
            float4 a4 = *(const float4*)&As[k][ng * 4];
            float4 b0 = *(const float4*)&Bs[k][og * 8];
            float4 b1 = *(const float4*)&Bs[k][og * 8 + 4];
            float av[4] = {a4.x, a4.y, a4.z, a4.w};
            float bv[8] = {b0.x, b0.y, b0.z, b0.w, b1.x, b1.y, b1.z, b1.w};
#pragma unroll
            for (int i = 0; i < 4; i++)
#pragma unroll
                for (int j = 0; j < 8; j++) acc[i][j] = fmaf(av[i], bv[j], acc[i][j]);
        }
        __syncthreads();
    }

    // epilogue: bias, store, per-feature stats
    float bvals[8];
#pragma unroll
    for (int j = 0; j < 8; j++) bvals[j] = bias[og * 8 + j];

    __shared__ float red[2][NF];
    if (tid < NF) { red[0][tid] = 0.f; red[1][tid] = 0.f; }
    __syncthreads();

    float rsum[8], rsq[8];
#pragma unroll
    for (int j = 0; j < 8; j++) { rsum[j] = 0.f; rsq[j] = 0.f; }

#pragma unroll
    for (int i = 0; i < 4; i++) {
        int n = n0 + ng * 4 + i;
        if (n < NN) {
            float v[8];
#pragma unroll
            for (int j = 0; j < 8; j++) {
                float t = acc[i][j] + bvals[j];
                v[j] = t;
                rsum[j] += t;
                rsq[j] += t * t;
            }
            *(float4*)&Z[n * NF + og * 8]     = make_float4(v[0], v[1], v[2], v[3]);
            *(float4*)&Z[n * NF + og * 8 + 4] = make_float4(v[4], v[5], v[6], v[7]);
        }
    }
#pragma unroll
    for (int j = 0; j < 8; j++) {
        atomicAdd(&red[0][og * 8 + j], rsum[j]);
        atomicAdd(&red[1][og * 8 + j], rsq[j]);
    }
    __syncthreads();
    if (tid < NF) {
        atomicAdd(&stats[tid], red[0][tid]);
        atomicAdd(&stats[NF + tid], red[1][tid]);
    }
}

// ---------------- GraphNorm + LeakyReLU (in-place) ----------------
__global__ __launch_bounds__(256) void k_norm(const float* __restrict__ stats,
                                              const float* __restrict__ gamma,
                                              const float* __restrict__ beta,
                                              const float* __restrict__ alpha,
                                              float* __restrict__ Z) {
    __shared__ float sc[NF], sh[NF];
    int tid = threadIdx.x;
    if (tid < NF) {
        float mean = stats[tid] * (1.0f / NN);
        float ex2 = stats[NF + tid] * (1.0f / NN);
        float a = alpha[tid];
        float am = a * mean;
        float var = ex2 - 2.f * am * mean + am * am;
        float inv = rsqrtf(var + GEPS);
        float g = gamma[tid] * inv;
        sc[tid] = g;
        sh[tid] = beta[tid] - g * am;
    }
    __syncthreads();
    int i = blockIdx.x * 256 + tid;   // exactly NN*NF/4 threads launched
    float4 z = ((const float4*)Z)[i];
    int f = (i & 31) * 4;
    float r0 = sc[f + 0] * z.x + sh[f + 0]; r0 = r0 > 0.f ? r0 : NEGS * r0;
    float r1 = sc[f + 1] * z.y + sh[f + 1]; r1 = r1 > 0.f ? r1 : NEGS * r1;
    float r2 = sc[f + 2] * z.z + sh[f + 2]; r2 = r2 > 0.f ? r2 : NEGS * r2;
    float r3 = sc[f + 3] * z.w + sh[f + 3]; r3 = r3 > 0.f ? r3 : NEGS * r3;
    ((float4*)Z)[i] = make_float4(r0, r1, r2, r3);
}

// ---------------- final layer: out = tanh(m@Wlo.T + blo + h@Wro.T)*0.5 ----------------
__global__ __launch_bounds__(256) void k_final(const float* __restrict__ m,
                                               const float* __restrict__ h,
                                               const float* __restrict__ Wlo,
                                               const float* __restrict__ blo,
                                               const float* __restrict__ Wro,
                                               float* __restrict__ out) {
    __shared__ __align__(16) float W[NOUT][256];
    __shared__ float bb[NOUT];
    int tid = threadIdx.x;
    for (int i = tid; i < NOUT * 256; i += 256) {
        int o = i >> 8, k = i & 255;
        W[o][k] = (k < NF) ? Wlo[o * NF + k] : Wro[o * NF + (k - NF)];
    }
    if (tid < NOUT) bb[tid] = blo[tid];
    __syncthreads();

    int node = blockIdx.x * 64 + (tid >> 2);
    int j = tid & 3;
    if (node >= NN) return;
    const float* src = (j < 2) ? m : h;
    int kbase = (j & 1) * 64;
    const float* row = &src[node * NF + kbase];
    float a0 = 0.f, a1 = 0.f, a2 = 0.f;
#pragma unroll
    for (int q = 0; q < 16; q++) {
        float4 v = *(const float4*)&row[q * 4];
        int k = j * 64 + q * 4;
        float4 w0 = *(const float4*)&W[0][k];
        float4 w1 = *(const float4*)&W[1][k];
        float4 w2 = *(const float4*)&W[2][k];
        a0 += v.x * w0.x + v.y * w0.y + v.z * w0.z + v.w * w0.w;
        a1 += v.x * w1.x + v.y * w1.y + v.z * w1.z + v.w * w1.w;
        a2 += v.x * w2.x + v.y * w2.y + v.z * w2.z + v.w * w2.w;
    }
    a0 += __shfl_down(a0, 2, 4); a0 += __shfl_down(a0, 1, 4);
    a1 += __shfl_down(a1, 2, 4); a1 += __shfl_down(a1, 1, 4);
    a2 += __shfl_down(a2, 2, 4); a2 += __shfl_down(a2, 1, 4);
    if (j == 0) {
        out[node * 3 + 0] = tanhf(a0 + bb[0]) * 0.5f;
        out[node * 3 + 1] = tanhf(a1 + bb[1]) * 0.5f;
        out[node * 3 + 2] = tanhf(a2 + bb[2]) * 0.5f;
    }
}

extern "C" void kernel_launch(void* const* d_in, const int* in_sizes, int n_in,
                              void* d_out, int out_size, void* d_ws, size_t ws_size,
                              hipStream_t stream) {
    const float* x     = (const float*)d_in[0];
    const int*   ei    = (const int*)d_in[1];
    const float* Wl    = (const float*)d_in[2];
    const float* bl    = (const float*)d_in[3];
    const float* Wr    = (const float*)d_in[4];
    const float* Wlo   = (const float*)d_in[5];
    const float* blo   = (const float*)d_in[6];
    const float* Wro   = (const float*)d_in[7];
    const float* gamma = (const float*)d_in[8];
    const float* beta  = (const float*)d_in[9];
    const float* alpha = (const float*)d_in[10];
    float* out = (float*)d_out;

    const int* esrc = ei;
    const int* edst = ei + NE;

    char* ws = (char*)d_ws;
    size_t off = 0;
    auto alloc = [&](size_t bytes) -> void* {
        void* p = ws + off;
        off += (bytes + 255) & ~(size_t)255;
        return p;
    };

    const int NB = (NN + 255) / 256;  // 391
    int*   counts  = (int*)alloc(NN * sizeof(int));
    int*   offsets = (int*)alloc((NN + 1) * sizeof(int));
    int*   cursor  = (int*)alloc(NN * sizeof(int));
    int*   bsums   = (int*)alloc(NB * sizeof(int));
    int*   csr     = (int*)alloc(NE * sizeof(int));
    float* mbuf    = (float*)alloc((size_t)NN * NF * sizeof(float));
    float* hA      = (float*)alloc((size_t)NN * NF * sizeof(float));
    float* hB      = (float*)alloc((size_t)NN * NF * sizeof(float));
    float* stats   = (float*)alloc(6 * 2 * NF * sizeof(float));

    hipMemsetAsync(counts, 0, NN * sizeof(int), stream);
    hipMemsetAsync(stats, 0, 6 * 2 * NF * sizeof(float), stream);

    // CSR build
    k_hist<<<(NE + 255) / 256, 256, 0, stream>>>(edst, counts);
    k_scan1<<<NB, 256, 0, stream>>>(counts, bsums);
    k_scan2<<<1, 512, 0, stream>>>(bsums, NB);
    k_scan3<<<NB, 256, 0, stream>>>(counts, bsums, offsets, cursor);
    k_scatter<<<(NE + 255) / 256, 256, 0, stream>>>(esrc, edst, cursor, csr);

    const int aggGrid  = (NN + 1) / 2;           // 2 nodes / block
    const int gemmGrid = (NN + 63) / 64;         // 1563
    const int normGrid = NN * NF / 4 / 256;      // 12500
    const int finGrid  = (NN + 63) / 64;

    const float* hcur = x;
    for (int L = 0; L < 6; ++L) {
        float* z = (L & 1) ? hB : hA;
        k_aggmax<<<aggGrid, 256, 0, stream>>>(hcur, offsets, csr, mbuf);
        k_gemm<<<gemmGrid, 256, 0, stream>>>(mbuf, hcur,
                                             Wl + (size_t)L * NF * NF,
                                             Wr + (size_t)L * NF * NF,
                                             bl + (size_t)L * NF,
                                             z, stats + (size_t)L * 2 * NF);
        k_norm<<<normGrid, 256, 0, stream>>>(stats + (size_t)L * 2 * NF,
                                             gamma + (size_t)L * NF,
                                             beta + (size_t)L * NF,
                                             alpha + (size_t)L * NF, z);
        hcur = z;
    }
    // final layer
    k_aggmax<<<aggGrid, 256, 0, stream>>>(hcur, offsets, csr, mbuf);
    k_final<<<finGrid, 256, 0, stream>>>(mbuf, hcur, Wlo, blo, Wro, out);
}